// Round 14
// baseline (662.597 us; speedup 1.0000x reference)
//
#include <hip/hip_runtime.h>
#include <hip/hip_bf16.h>

#define BB 16384
#define KK 3
#define DD 1024
#define HH 16

typedef __attribute__((ext_vector_type(8))) short bf16x8;
typedef __attribute__((ext_vector_type(4))) float f32x4;
typedef __attribute__((ext_vector_type(16))) float f32x16;
typedef unsigned int u32;

__device__ __forceinline__ void load_lds16(const void* g, void* l) {
  __builtin_amdgcn_global_load_lds(
      (const __attribute__((address_space(1))) u32*)g,
      (__attribute__((address_space(3))) u32*)l,
      16, 0, 0);
}

__device__ __forceinline__ unsigned short f2bf(float f) {
  __hip_bfloat16 h = __float2bfloat16(f);
  unsigned short u;
  __builtin_memcpy(&u, &h, 2);
  return u;
}

__device__ __forceinline__ float bf2f(unsigned short u) {
  union { float f; u32 i; } cv;
  cv.i = ((u32)u) << 16;
  return cv.f;
}

// ---------------------------------------------------------------- input casts, branch-free block split
__global__ __launch_bounds__(256)
void cast_inputs(const float* __restrict__ tokens, const float* __restrict__ ctx,
                 unsigned short* __restrict__ Xb, unsigned short* __restrict__ Cin) {
  const bool isCtx = blockIdx.x >= 3072;
  const float* src = isCtx ? ctx : tokens;
  unsigned short* dst = isCtx ? Cin : Xb;
  const int inner = isCtx ? (blockIdx.x - 3072) : blockIdx.x;
  const int base = inner * 4096 + threadIdx.x;
#pragma unroll
  for (int k = 0; k < 16; ++k) {
    const int i = base + k * 256;
    float4 v = ((const float4*)src)[i];
    ushort4 o;
    o.x = f2bf(v.x); o.y = f2bf(v.y); o.z = f2bf(v.z); o.w = f2bf(v.w);
    ((ushort4*)dst)[i] = o;
  }
}

// ---------------------------------------------------------------- all weight casts in one launch
__global__ __launch_bounds__(256)
void cast_weights5(const float* __restrict__ Wq, const float* __restrict__ Wk,
                   const float* __restrict__ Wv, const float* __restrict__ Wc,
                   const float* __restrict__ Wo,
                   unsigned short* __restrict__ Wqkv,
                   unsigned short* __restrict__ Wcb,
                   unsigned short* __restrict__ Wob) {
  const int mat = blockIdx.x >> 8;
  const int inner = blockIdx.x & 255;
  const float* src = mat == 0 ? Wq : mat == 1 ? Wk : mat == 2 ? Wv
                   : mat == 3 ? Wc : Wo;
  unsigned short* dst = mat <= 2 ? Wqkv + (size_t)mat * DD * DD
                      : mat == 3 ? Wcb : Wob;
  const int base = inner * 1024 + threadIdx.x;
#pragma unroll
  for (int k = 0; k < 4; ++k) {
    const int i = base + k * 256;
    float4 v = ((const float4*)src)[i];
    ushort4 o;
    o.x = f2bf(v.x); o.y = f2bf(v.y); o.z = f2bf(v.z); o.w = f2bf(v.w);
    ((ushort4*)dst)[i] = o;
  }
}

// ---------------------------------------------------------------- shared GEMM body, 32x32x16 MFMA
// R7-proven pipeline (4-slot 32KB ring, stage t+3, vmcnt(8) steady, ONE
// barrier per K32-tile, no lgkm drains) with the faster 32x32x16 bf16 pipe
// (m119: 2495 TF vs 2176) and half the MFMA instruction count.
// Slot layout: A [128 lines][128B] at +0, B [128 lines][128B] at +16384
// (R13 BUG was B at +32768 = next slot's A region — fixed).
// Line holds rows {line, line+128}: logical chunk q = (row>>7)*4 + kchunk,
// phys = q ^ (line&7); pre-swizzled gload source, swizzled ds_read.
// Wave-tile 128x64 = 4x2 sub-tiles of 32x32; acc = 8 x f32x16 = 128 VGPR.
// Operand frags (K=16 step s): lane l -> row/col = l&31, k = 16s + 8*(l>>5)
// + 0..7 (consistent A/B mapping => dot product invariant to k-permutation).
// C/D layout [m74/m101-verified]: col = lane&31,
//   row = (reg&3) + 8*(reg>>2) + 4*(lane>>5).
template <bool OUT_F32>
__device__ __forceinline__ void gemm_body32(char* lds,
    const __hip_bfloat16* __restrict__ A, const __hip_bfloat16* __restrict__ Bt,
    const float* __restrict__ bias, int biasOff, void* __restrict__ Cout,
    int tm, int tn, int N, int K) {
  const int tid = threadIdx.x;
  const int l = tid & 63;
  const int w = tid >> 6;
  const int wm = w >> 2;   // 0..1
  const int wn = w & 3;    // 0..3
  const int l31 = l & 31;
  const int hk = l >> 5;   // k-half within K16
  const int l7 = l31 & 7;

  const int aLine = l31 << 7;

  const size_t strideK = (size_t)K * 2;
  const char* Ab = (const char*)A + (size_t)tm * 256 * strideK;
  const char* Bb = (const char*)Bt + (size_t)tn * 256 * strideK;
  const int q = (tid & 7) ^ ((tid >> 3) & 7);
  const size_t g0 = (size_t)((q >> 2) * 128 + (tid >> 3)) * strideK + (q & 3) * 16;
  const size_t g1 = g0 + (size_t)64 * strideK;
  const int sld = tid << 4;

  f32x16 acc[4][2] = {};
  const int nkt = K >> 5;

#define STAGE_AB(T)                                                       \
  {                                                                       \
    char* sb = lds + (((T) & 3) << 15);                                   \
    const char* ga = Ab + ((size_t)(T) << 6);                             \
    const char* gb = Bb + ((size_t)(T) << 6);                             \
    load_lds16(ga + g0, sb + sld);                                        \
    load_lds16(ga + g1, sb + 8192 + sld);                                 \
    load_lds16(gb + g0, sb + 16384 + sld);                                \
    load_lds16(gb + g1, sb + 24576 + sld);                                \
  }

  STAGE_AB(0);
  STAGE_AB(1);
  STAGE_AB(2);

  for (int kt = 0; kt < nkt; ++kt) {
    if (kt <= nkt - 3)
      asm volatile("s_waitcnt vmcnt(8)" ::: "memory");
    else if (kt == nkt - 2)
      asm volatile("s_waitcnt vmcnt(4)" ::: "memory");
    else
      asm volatile("s_waitcnt vmcnt(0)" ::: "memory");
    __builtin_amdgcn_s_barrier();
    asm volatile("" ::: "memory");

    const char* slot = lds + ((kt & 3) << 15);
    bf16x8 af[4][2], bfr[2][2];
#pragma unroll
    for (int n = 0; n < 2; ++n) {
      const int cIdx = (wn << 1) + n;
      const char* bp = slot + 16384 + (((cIdx & 3) << 5) << 7) + aLine;  // FIXED
#pragma unroll
      for (int s = 0; s < 2; ++s)
        bfr[n][s] = *(const bf16x8*)(bp +
            (((((cIdx >> 2) << 2) + (s << 1) + hk) ^ l7) << 4));
    }
#pragma unroll
    for (int m = 0; m < 4; ++m) {
      const char* ap = slot + ((m << 5) << 7) + aLine;
#pragma unroll
      for (int s = 0; s < 2; ++s)
        af[m][s] = *(const bf16x8*)(ap +
            ((((wm << 2) + (s << 1) + hk) ^ l7) << 4));
    }

    if (kt + 3 < nkt) STAGE_AB(kt + 3);

    __builtin_amdgcn_s_setprio(1);
#pragma unroll
    for (int s = 0; s < 2; ++s)
#pragma unroll
      for (int m = 0; m < 4; ++m)
#pragma unroll
        for (int n = 0; n < 2; ++n)
          acc[m][n] = __builtin_amdgcn_mfma_f32_32x32x16_bf16(
              af[m][s], bfr[n][s], acc[m][n], 0, 0, 0);
    __builtin_amdgcn_s_setprio(0);
  }
#undef STAGE_AB

  // epilogue: col = l&31 (in cbase), row = (j&3) + 8*(j>>2) + 4*hk
  const int cb0 = tn * 256 + (wn << 6) + l31;
  float b2[2];
#pragma unroll
  for (int n = 0; n < 2; ++n) b2[n] = bias[cb0 + (n << 5) - biasOff];
  const size_t rbase = (size_t)tm * 256 + (wm << 7) + (hk << 2);
#pragma unroll
  for (int m = 0; m < 4; ++m) {
#pragma unroll
    for (int j = 0; j < 16; ++j) {
      const size_t row = rbase + (m << 5) + (j & 3) + ((j >> 2) << 3);
#pragma unroll
      for (int n = 0; n < 2; ++n) {
        const int col = cb0 + (n << 5);
        float v = acc[m][n][j] + b2[n];
        if (OUT_F32)
          ((float*)Cout)[row * N + col] = v;
        else
          ((unsigned short*)Cout)[row * N + col] = f2bf(v);
      }
    }
  }
}

// ---------------------------------------------------------------- QKV projection
__global__ __launch_bounds__(512, 2)
void gemm_qkv(const __hip_bfloat16* __restrict__ Xb,
              const __hip_bfloat16* __restrict__ Wqkv,
              const float* __restrict__ bq, const float* __restrict__ bk,
              const float* __restrict__ bv,
              unsigned short* __restrict__ QKV) {
  __shared__ __align__(128) char lds[131072];
  const int nwg = (BB * KK / 256) * (3 * DD / 256);  // 2304
  int bid = blockIdx.x;
  bid = (bid & 7) * (nwg >> 3) + (bid >> 3);
  const int tm = bid / 12, tn = bid % 12;
  const int which = tn >> 2;  // 0:q 1:k 2:v
  const float* bp = which == 0 ? bq : which == 1 ? bk : bv;
  gemm_body32<false>(lds, Xb, Wqkv, bp, which << 10, QKV, tm, tn, 3 * DD, DD);
}

// ---------------------------------------------------------------- ctx projection
__global__ __launch_bounds__(512, 2)
void gemm_ctx(const __hip_bfloat16* __restrict__ Cin,
              const __hip_bfloat16* __restrict__ Wcb,
              const float* __restrict__ bc,
              unsigned short* __restrict__ Cpr) {
  __shared__ __align__(128) char lds[131072];
  const int nwg = (BB / 256) * (DD / 256);  // 256
  int bid = blockIdx.x;
  bid = (bid & 7) * (nwg >> 3) + (bid >> 3);
  gemm_body32<false>(lds, Cin, Wcb, bc, 0, Cpr, bid / 4, bid % 4, DD, DD);
}

// ---------------------------------------------------------------- output projection -> fp32 d_out
__global__ __launch_bounds__(512, 2)
void gemm_outp(const __hip_bfloat16* __restrict__ A,
               const __hip_bfloat16* __restrict__ Wob,
               const float* __restrict__ bo, float* __restrict__ C) {
  __shared__ __align__(128) char lds[131072];
  const int nwg = (BB * KK / 256) * (DD / 256);  // 768
  int bid = blockIdx.x;
  bid = (bid & 7) * (nwg >> 3) + (bid >> 3);
  gemm_body32<true>(lds, A, Wob, bo, 0, C, bid / 4, bid % 4, DD, DD);
}

// ---------------------------------------------------------------- attention
// 8 lanes per (b,h); lane x handles dims 8x..8x+7 via 16B loads.
__global__ __launch_bounds__(256)
void attn_kernel(const unsigned short* __restrict__ QKV,  // (B*3) x 3072
                 const unsigned short* __restrict__ Cp,   // B x 1024
                 unsigned short* __restrict__ Out) {      // (B*3) x 1024
  const int t = threadIdx.x;
  const int grp = (blockIdx.x << 5) + (t >> 3);  // 32 groups/block
  const int x = t & 7;
  const int b = grp >> 4;   // H = 16
  const int h = grp & 15;

  const size_t col = (size_t)h * 64 + (x << 3);
  const size_t qbase = (size_t)b * 3 * 3072 + col;

  bf16x8 cu = *(const bf16x8*)&Cp[(size_t)b * 1024 + col];
  float c[8];
#pragma unroll
  for (int d = 0; d < 8; ++d) c[d] = bf2f((unsigned short)cu[d]);

  float q[3][8], kc[3][8], vc[3][8];
#pragma unroll
  for (int i = 0; i < 3; ++i) {
    bf16x8 qu = *(const bf16x8*)&QKV[qbase + (size_t)i * 3072];
    bf16x8 ku = *(const bf16x8*)&QKV[qbase + (size_t)i * 3072 + 1024];
    bf16x8 vu = *(const bf16x8*)&QKV[qbase + (size_t)i * 3072 + 2048];
#pragma unroll
    for (int d = 0; d < 8; ++d) {
      q[i][d] = bf2f((unsigned short)qu[d]);
      kc[i][d] = bf2f((unsigned short)ku[d]) * c[d];
      vc[i][d] = bf2f((unsigned short)vu[d]) * c[d];
    }
  }

  float s[9];
#pragma unroll
  for (int i = 0; i < 3; ++i)
#pragma unroll
    for (int j = 0; j < 3; ++j) {
      float acc = 0.f;
#pragma unroll
      for (int d = 0; d < 8; ++d) acc += q[i][d] * kc[j][d];
      s[i * 3 + j] = acc;
    }

#pragma unroll
  for (int off = 4; off > 0; off >>= 1)
#pragma unroll
    for (int e = 0; e < 9; ++e)
      s[e] += __shfl_xor(s[e], off, 64);

  const float scale = 0.125f;  // 1/sqrt(64)
#pragma unroll
  for (int i = 0; i < 3; ++i) {
    float s0 = s[i * 3 + 0] * scale;
    float s1 = s[i * 3 + 1] * scale;
    float s2 = s[i * 3 + 2] * scale;
    float m = fmaxf(fmaxf(s0, s1), s2);
    float p0 = expf(s0 - m), p1 = expf(s1 - m), p2 = expf(s2 - m);
    float inv = 1.0f / (p0 + p1 + p2);
    bf16x8 o;
#pragma unroll
    for (int d = 0; d < 8; ++d)
      o[d] = (short)f2bf((p0 * vc[0][d] + p1 * vc[1][d] + p2 * vc[2][d]) * inv);
    *(bf16x8*)&Out[(size_t)(b * 3 + i) * 1024 + col] = o;
  }
}

// ---------------------------------------------------------------- launch
extern "C" void kernel_launch(void* const* d_in, const int* in_sizes, int n_in,
                              void* d_out, int out_size, void* d_ws, size_t ws_size,
                              hipStream_t stream) {
  const float* tokens = (const float*)d_in[0];
  const float* ctx    = (const float*)d_in[1];
  const float* Wq     = (const float*)d_in[2];
  const float* bq     = (const float*)d_in[3];
  const float* Wk     = (const float*)d_in[4];
  const float* bk     = (const float*)d_in[5];
  const float* Wv     = (const float*)d_in[6];
  const float* bv     = (const float*)d_in[7];
  const float* Wc     = (const float*)d_in[8];
  const float* bc     = (const float*)d_in[9];
  const float* Wo     = (const float*)d_in[10];
  const float* bo     = (const float*)d_in[11];

  const int M  = BB * KK;   // 49152 token rows
  const int Mc = BB;        // 16384 ctx rows
  const int D  = DD;        // 1024

  char* p = (char*)d_ws;
  auto carve = [&](size_t bytes) {
    char* r = p;
    p += (bytes + 255) & ~(size_t)255;
    return r;
  };
  unsigned short* Xb   = (unsigned short*)carve((size_t)M * D * 2);   // tokens bf16; reused as attn out
  unsigned short* Cin  = (unsigned short*)carve((size_t)Mc * D * 2);
  unsigned short* Wqkv = (unsigned short*)carve((size_t)3 * D * D * 2);
  unsigned short* Wcb  = (unsigned short*)carve((size_t)D * D * 2);
  unsigned short* Wob  = (unsigned short*)carve((size_t)D * D * 2);
  unsigned short* QKV  = (unsigned short*)carve((size_t)M * 3 * D * 2);
  unsigned short* Cpr  = (unsigned short*)carve((size_t)Mc * D * 2);

  // 1) input casts (tokens + ctx), one branch-free launch
  hipLaunchKernelGGL(cast_inputs, dim3(4096), dim3(256), 0, stream,
                     tokens, ctx, Xb, Cin);
  // 2) weight casts, one launch
  hipLaunchKernelGGL(cast_weights5, dim3(1280), dim3(256), 0, stream,
                     Wq, Wk, Wv, Wc, Wo, Wqkv, Wcb, Wob);
  // 3) QKV projection (2304 blocks)
  hipLaunchKernelGGL(gemm_qkv, dim3(2304), dim3(512), 0, stream,
                     (const __hip_bfloat16*)Xb, (const __hip_bfloat16*)Wqkv,
                     bq, bk, bv, QKV);
  // 4) ctx projection (256 blocks)
  hipLaunchKernelGGL(gemm_ctx, dim3(256), dim3(512), 0, stream,
                     (const __hip_bfloat16*)Cin, (const __hip_bfloat16*)Wcb,
                     bc, Cpr);
  // 5) attention (writes into Xb, dead after gemm_qkv)
  hipLaunchKernelGGL(attn_kernel, dim3(BB * HH / 32), dim3(256), 0, stream,
                     QKV, Cpr, Xb);
  // 6) output projection -> fp32 d_out with bias (768 blocks)
  hipLaunchKernelGGL(gemm_outp, dim3(768), dim3(512), 0, stream,
                     (const __hip_bfloat16*)Xb, (const __hip_bfloat16*)Wob,
                     bo, (float*)d_out);
}

// Round 16
// 596.843 us; speedup vs baseline: 1.1102x; 1.1102x over previous
//
#include <hip/hip_runtime.h>
#include <hip/hip_bf16.h>

#define BB 16384
#define KK 3
#define DD 1024
#define HH 16

typedef __attribute__((ext_vector_type(8))) short bf16x8;
typedef __attribute__((ext_vector_type(4))) float f32x4;
typedef unsigned int u32;

__device__ __forceinline__ void load_lds16(const void* g, void* l) {
  __builtin_amdgcn_global_load_lds(
      (const __attribute__((address_space(1))) u32*)g,
      (__attribute__((address_space(3))) u32*)l,
      16, 0, 0);
}

__device__ __forceinline__ unsigned short f2bf(float f) {
  __hip_bfloat16 h = __float2bfloat16(f);
  unsigned short u;
  __builtin_memcpy(&u, &h, 2);
  return u;
}

__device__ __forceinline__ float bf2f(unsigned short u) {
  union { float f; u32 i; } cv;
  cv.i = ((u32)u) << 16;
  return cv.f;
}

// ---------------------------------------------------------------- ALL casts in one dispatch
// blocks    0..3071: tokens (3072 blocks x 4096 float4, 16 iters/thread)
// blocks 3072..4095: ctx    (1024 blocks x 4096 float4, 16 iters/thread)
// blocks 4096..5375: weights (5 mats x 256 blocks x 1024 float4, 4 iters)
// [R15 BUG: ctx was given only 256 blocks -> 3/4 of Cin left poisoned. Fixed.]
__global__ __launch_bounds__(256)
void cast_all(const float* __restrict__ tokens, const float* __restrict__ ctx,
              const float* __restrict__ Wq, const float* __restrict__ Wk,
              const float* __restrict__ Wv, const float* __restrict__ Wc,
              const float* __restrict__ Wo,
              unsigned short* __restrict__ Xb, unsigned short* __restrict__ Cin,
              unsigned short* __restrict__ Wqkv, unsigned short* __restrict__ Wcb,
              unsigned short* __restrict__ Wob) {
  const int blk = blockIdx.x;
  if (blk < 4096) {
    const bool isCtx = blk >= 3072;
    const float* src = isCtx ? ctx : tokens;
    unsigned short* dst = isCtx ? Cin : Xb;
    const int inner = isCtx ? (blk - 3072) : blk;
    const int base = inner * 4096 + threadIdx.x;
#pragma unroll
    for (int k = 0; k < 16; ++k) {
      const int i = base + k * 256;
      float4 v = ((const float4*)src)[i];
      ushort4 o;
      o.x = f2bf(v.x); o.y = f2bf(v.y); o.z = f2bf(v.z); o.w = f2bf(v.w);
      ((ushort4*)dst)[i] = o;
    }
  } else {
    const int wblk = blk - 4096;
    const int mat = wblk >> 8;
    const int inner = wblk & 255;
    const float* src = mat == 0 ? Wq : mat == 1 ? Wk : mat == 2 ? Wv
                     : mat == 3 ? Wc : Wo;
    unsigned short* dst = mat <= 2 ? Wqkv + (size_t)mat * DD * DD
                        : mat == 3 ? Wcb : Wob;
    const int base = inner * 1024 + threadIdx.x;
#pragma unroll
    for (int k = 0; k < 4; ++k) {
      const int i = base + k * 256;
      float4 v = ((const float4*)src)[i];
      ushort4 o;
      o.x = f2bf(v.x); o.y = f2bf(v.y); o.z = f2bf(v.z); o.w = f2bf(v.w);
      ((ushort4*)dst)[i] = o;
    }
  }
}

// ---------------------------------------------------------------- shared 8-phase GEMM body (R12-proven: QKV 320us / 43% MfmaUtil / 0 conflicts)
// 256x256 tile, BK=64, 8 waves (2Mx4N), wave-tile 128x64, 16x16x32 MFMA.
// LDS 128KB (2 buffers x (A 32KB + B 32KB)). Per 2-K-tile iteration, 8 phases:
//   {ds_read quadrant frags | stage 1 half-tile | [vmcnt(4) @P4/P8] | sbar |
//    lgkm0 | setprio1 16 MFMA setprio0 | sbar}
// Stages run 3-5 half-tiles ahead (P1/P2: t1-B, P3/P4: t2-A, P5/P6: t2-B,
// P7/P8: t3-A). Chunk-XOR swizzle phys = logical ^ (row&7), both-sides
// (pre-swizzled gload source + swizzled ds_read, linear dest): conflicts = 0.
template <bool OUT_F32>
__device__ __forceinline__ void gemm_body8(char* lds,
    const __hip_bfloat16* __restrict__ A, const __hip_bfloat16* __restrict__ Bt,
    const float* __restrict__ bias, int biasOff, void* __restrict__ Cout,
    int tm, int tn, int N, int K) {
  const int tid = threadIdx.x;
  const int l = tid & 63;
  const int w = tid >> 6;
  const int wm = w >> 2;
  const int wn = w & 3;
  const int l15 = l & 15;
  const int g = l >> 4;
  const int l7 = l15 & 7;

  const int cs0 = ((g ^ l7) << 4);
  const int cs1 = (((4 | g) ^ l7) << 4);
  const int aRowB = ((wm << 7) + l15) << 7;
  const int bColB = 32768 + (((wn << 6) + l15) << 7);

  const size_t strideK = (size_t)K * 2;
  const char* Ab = (const char*)A + (size_t)tm * 256 * strideK;
  const char* Bb = (const char*)Bt + (size_t)tn * 256 * strideK;
  const size_t sOff = (size_t)(tid >> 3) * strideK +
                      (size_t)(((tid & 7) ^ ((tid >> 3) & 7)) << 4);
  const int sldst = tid << 4;

  char* const sl0 = lds;
  char* const sl1 = lds + 65536;

  f32x4 acc[8][4] = {};
  bf16x8 aF[16], bF[8];
  const int njt = K >> 7;

#define STG_A(T, H)                                                        \
  {                                                                        \
    char* d = lds + (((T) & 1) << 16) + ((H) << 14) + sldst;               \
    const char* s = Ab + ((size_t)(T) << 7) +                              \
                    ((size_t)((H) << 7)) * strideK + sOff;                 \
    load_lds16(s, d);                                                      \
    load_lds16(s + 64 * strideK, d + 8192);                                \
  }
#define STG_B(T, H)                                                        \
  {                                                                        \
    char* d = lds + (((T) & 1) << 16) + 32768 + ((H) << 14) + sldst;       \
    const char* s = Bb + ((size_t)(T) << 7) +                              \
                    ((size_t)((H) << 7)) * strideK + sOff;                 \
    load_lds16(s, d);                                                      \
    load_lds16(s + 64 * strideK, d + 8192);                                \
  }
#define RD_A2(SB, m)                                                       \
  aF[2 * (m)] = *(const bf16x8*)((SB) + aRowB + ((m) << 11) + cs0);        \
  aF[2 * (m) + 1] = *(const bf16x8*)((SB) + aRowB + ((m) << 11) + cs1);
#define RD_B2(SB, n)                                                       \
  bF[2 * (n)] = *(const bf16x8*)((SB) + bColB + ((n) << 11) + cs0);        \
  bF[2 * (n) + 1] = *(const bf16x8*)((SB) + bColB + ((n) << 11) + cs1);
#define MFMA_Q(MH, NH)                                                     \
  __builtin_amdgcn_s_setprio(1);                                           \
  _Pragma("unroll") for (int mm = 0; mm < 4; ++mm)                         \
      _Pragma("unroll") for (int nn = 0; nn < 2; ++nn)                     \
          _Pragma("unroll") for (int kh = 0; kh < 2; ++kh)                 \
              acc[(MH)*4 + mm][(NH)*2 + nn] =                              \
                  __builtin_amdgcn_mfma_f32_16x16x32_bf16(                 \
                      aF[2 * ((MH)*4 + mm) + kh],                          \
                      bF[2 * ((NH)*2 + nn) + kh],                          \
                      acc[(MH)*4 + mm][(NH)*2 + nn], 0, 0, 0);             \
  __builtin_amdgcn_s_setprio(0);
#define BAR  __builtin_amdgcn_s_barrier(); asm volatile("" ::: "memory");
#define LGKM0 asm volatile("s_waitcnt lgkmcnt(0)" ::: "memory");

  STG_A(0, 0); STG_A(0, 1); STG_B(0, 0); STG_B(0, 1);
  STG_A(1, 0); STG_A(1, 1);
  asm volatile("s_waitcnt vmcnt(4)" ::: "memory");
  BAR

  for (int j = 0; j < njt; ++j) {
    const int t1 = 2 * j + 1, t2 = 2 * j + 2, t3 = 2 * j + 3;
    const bool full = (j < njt - 1);

    RD_B2(sl0, 0) RD_B2(sl0, 1)
    RD_A2(sl0, 0) RD_A2(sl0, 1) RD_A2(sl0, 2) RD_A2(sl0, 3)
    STG_B(t1, 0)
    BAR LGKM0 MFMA_Q(0, 0) BAR
    RD_A2(sl0, 4) RD_A2(sl0, 5) RD_A2(sl0, 6) RD_A2(sl0, 7)
    STG_B(t1, 1)
    BAR LGKM0 MFMA_Q(1, 0) BAR
    RD_B2(sl0, 2) RD_B2(sl0, 3)
    if (full) STG_A(t2, 0)
    BAR LGKM0 MFMA_Q(0, 1) BAR
    if (full) STG_A(t2, 1)
    if (full) { asm volatile("s_waitcnt vmcnt(4)" ::: "memory"); }
    else      { asm volatile("s_waitcnt vmcnt(0)" ::: "memory"); }
    BAR MFMA_Q(1, 1) BAR

    RD_B2(sl1, 0) RD_B2(sl1, 1)
    RD_A2(sl1, 0) RD_A2(sl1, 1) RD_A2(sl1, 2) RD_A2(sl1, 3)
    if (full) STG_B(t2, 0)
    BAR LGKM0 MFMA_Q(0, 0) BAR
    RD_A2(sl1, 4) RD_A2(sl1, 5) RD_A2(sl1, 6) RD_A2(sl1, 7)
    if (full) STG_B(t2, 1)
    BAR LGKM0 MFMA_Q(1, 0) BAR
    RD_B2(sl1, 2) RD_B2(sl1, 3)
    if (full) STG_A(t3, 0)
    BAR LGKM0 MFMA_Q(0, 1) BAR
    if (full) STG_A(t3, 1)
    if (full) { asm volatile("s_waitcnt vmcnt(4)" ::: "memory"); }
    else      { asm volatile("s_waitcnt vmcnt(0)" ::: "memory"); }
    BAR MFMA_Q(1, 1) BAR
  }
#undef STG_A
#undef STG_B
#undef RD_A2
#undef RD_B2
#undef MFMA_Q
#undef BAR
#undef LGKM0

  // epilogue: C/D layout col = lane&15, row = (lane>>4)*4 + reg  [m89-verified]
  const int cbase = tn * 256 + (wn << 6) + l15;
  float b4[4];
#pragma unroll
  for (int n = 0; n < 4; ++n) b4[n] = bias[cbase + (n << 4) - biasOff];
  const size_t rbase = (size_t)tm * 256 + (wm << 7) + ((l >> 4) << 2);
#pragma unroll
  for (int m = 0; m < 8; ++m) {
#pragma unroll
    for (int j = 0; j < 4; ++j) {
      const size_t row = rbase + (m << 4) + j;
#pragma unroll
      for (int n = 0; n < 4; ++n) {
        const int col = cbase + (n << 4);
        float v = acc[m][n][j] + b4[n];
        if (OUT_F32)
          ((float*)Cout)[row * N + col] = v;
        else
          ((unsigned short*)Cout)[row * N + col] = f2bf(v);
      }
    }
  }
}

// ---------------------------------------------------------------- QKV projection (bias selected per column range)
__global__ __launch_bounds__(512, 2)
void gemm_qkv(const __hip_bfloat16* __restrict__ Xb,
              const __hip_bfloat16* __restrict__ Wqkv,
              const float* __restrict__ bq, const float* __restrict__ bk,
              const float* __restrict__ bv,
              unsigned short* __restrict__ QKV) {
  __shared__ __align__(128) char lds[131072];
  const int nwg = (BB * KK / 256) * (3 * DD / 256);  // 2304
  int bid = blockIdx.x;
  bid = (bid & 7) * (nwg >> 3) + (bid >> 3);
  const int tm = bid / 12, tn = bid % 12;
  const int which = tn >> 2;  // 0:q 1:k 2:v
  const float* bp = which == 0 ? bq : which == 1 ? bk : bv;
  gemm_body8<false>(lds, Xb, Wqkv, bp, which << 10, QKV, tm, tn, 3 * DD, DD);
}

// ---------------------------------------------------------------- ctx projection
__global__ __launch_bounds__(512, 2)
void gemm_ctx(const __hip_bfloat16* __restrict__ Cin,
              const __hip_bfloat16* __restrict__ Wcb,
              const float* __restrict__ bc,
              unsigned short* __restrict__ Cpr) {
  __shared__ __align__(128) char lds[131072];
  const int nwg = (BB / 256) * (DD / 256);  // 256
  int bid = blockIdx.x;
  bid = (bid & 7) * (nwg >> 3) + (bid >> 3);
  gemm_body8<false>(lds, Cin, Wcb, bc, 0, Cpr, bid / 4, bid % 4, DD, DD);
}

// ---------------------------------------------------------------- output projection -> fp32 d_out
__global__ __launch_bounds__(512, 2)
void gemm_outp(const __hip_bfloat16* __restrict__ A,
               const __hip_bfloat16* __restrict__ Wob,
               const float* __restrict__ bo, float* __restrict__ C) {
  __shared__ __align__(128) char lds[131072];
  const int nwg = (BB * KK / 256) * (DD / 256);  // 768
  int bid = blockIdx.x;
  bid = (bid & 7) * (nwg >> 3) + (bid >> 3);
  gemm_body8<true>(lds, A, Wob, bo, 0, C, bid / 4, bid % 4, DD, DD);
}

// ---------------------------------------------------------------- attention
// 8 lanes per (b,h); lane x handles dims 8x..8x+7 via 16B loads.
__global__ __launch_bounds__(256)
void attn_kernel(const unsigned short* __restrict__ QKV,  // (B*3) x 3072
                 const unsigned short* __restrict__ Cp,   // B x 1024
                 unsigned short* __restrict__ Out) {      // (B*3) x 1024
  const int t = threadIdx.x;
  const int grp = (blockIdx.x << 5) + (t >> 3);  // 32 groups/block
  const int x = t & 7;
  const int b = grp >> 4;   // H = 16
  const int h = grp & 15;

  const size_t col = (size_t)h * 64 + (x << 3);
  const size_t qbase = (size_t)b * 3 * 3072 + col;

  bf16x8 cu = *(const bf16x8*)&Cp[(size_t)b * 1024 + col];
  float c[8];
#pragma unroll
  for (int d = 0; d < 8; ++d) c[d] = bf2f((unsigned short)cu[d]);

  float q[3][8], kc[3][8], vc[3][8];
#pragma unroll
  for (int i = 0; i < 3; ++i) {
    bf16x8 qu = *(const bf16x8*)&QKV[qbase + (size_t)i * 3072];
    bf16x8 ku = *(const bf16x8*)&QKV[qbase + (size_t)i * 3072 + 1024];
    bf16x8 vu = *(const bf16x8*)&QKV[qbase + (size_t)i * 3072 + 2048];
#pragma unroll
    for (int d = 0; d < 8; ++d) {
      q[i][d] = bf2f((unsigned short)qu[d]);
      kc[i][d] = bf2f((unsigned short)ku[d]) * c[d];
      vc[i][d] = bf2f((unsigned short)vu[d]) * c[d];
    }
  }

  float s[9];
#pragma unroll
  for (int i = 0; i < 3; ++i)
#pragma unroll
    for (int j = 0; j < 3; ++j) {
      float acc = 0.f;
#pragma unroll
      for (int d = 0; d < 8; ++d) acc += q[i][d] * kc[j][d];
      s[i * 3 + j] = acc;
    }

#pragma unroll
  for (int off = 4; off > 0; off >>= 1)
#pragma unroll
    for (int e = 0; e < 9; ++e)
      s[e] += __shfl_xor(s[e], off, 64);

  const float scale = 0.125f;  // 1/sqrt(64)
#pragma unroll
  for (int i = 0; i < 3; ++i) {
    float s0 = s[i * 3 + 0] * scale;
    float s1 = s[i * 3 + 1] * scale;
    float s2 = s[i * 3 + 2] * scale;
    float m = fmaxf(fmaxf(s0, s1), s2);
    float p0 = expf(s0 - m), p1 = expf(s1 - m), p2 = expf(s2 - m);
    float inv = 1.0f / (p0 + p1 + p2);
    bf16x8 o;
#pragma unroll
    for (int d = 0; d < 8; ++d)
      o[d] = (short)f2bf((p0 * vc[0][d] + p1 * vc[1][d] + p2 * vc[2][d]) * inv);
    *(bf16x8*)&Out[(size_t)(b * 3 + i) * 1024 + col] = o;
  }
}

// ---------------------------------------------------------------- launch
extern "C" void kernel_launch(void* const* d_in, const int* in_sizes, int n_in,
                              void* d_out, int out_size, void* d_ws, size_t ws_size,
                              hipStream_t stream) {
  const float* tokens = (const float*)d_in[0];
  const float* ctx    = (const float*)d_in[1];
  const float* Wq     = (const float*)d_in[2];
  const float* bq     = (const float*)d_in[3];
  const float* Wk     = (const float*)d_in[4];
  const float* bk     = (const float*)d_in[5];
  const float* Wv     = (const float*)d_in[6];
  const float* bv     = (const float*)d_in[7];
  const float* Wc     = (const float*)d_in[8];
  const float* bc     = (const float*)d_in[9];
  const float* Wo     = (const float*)d_in[10];
  const float* bo     = (const float*)d_in[11];

  const int M  = BB * KK;   // 49152 token rows
  const int Mc = BB;        // 16384 ctx rows
  const int D  = DD;        // 1024

  char* p = (char*)d_ws;
  auto carve = [&](size_t bytes) {
    char* r = p;
    p += (bytes + 255) & ~(size_t)255;
    return r;
  };
  unsigned short* Xb   = (unsigned short*)carve((size_t)M * D * 2);   // tokens bf16; reused as attn out
  unsigned short* Cin  = (unsigned short*)carve((size_t)Mc * D * 2);
  unsigned short* Wqkv = (unsigned short*)carve((size_t)3 * D * D * 2);
  unsigned short* Wcb  = (unsigned short*)carve((size_t)D * D * 2);
  unsigned short* Wob  = (unsigned short*)carve((size_t)D * D * 2);
  unsigned short* QKV  = (unsigned short*)carve((size_t)M * 3 * D * 2);
  unsigned short* Cpr  = (unsigned short*)carve((size_t)Mc * D * 2);

  // 1) ALL casts (tokens + ctx + 5 weights) in one dispatch (5376 blocks)
  hipLaunchKernelGGL(cast_all, dim3(5376), dim3(256), 0, stream,
                     tokens, ctx, Wq, Wk, Wv, Wc, Wo,
                     Xb, Cin, Wqkv, Wcb, Wob);
  // 2) QKV projection (2304 blocks)
  hipLaunchKernelGGL(gemm_qkv, dim3(2304), dim3(512), 0, stream,
                     (const __hip_bfloat16*)Xb, (const __hip_bfloat16*)Wqkv,
                     bq, bk, bv, QKV);
  // 3) ctx projection (256 blocks)
  hipLaunchKernelGGL(gemm_ctx, dim3(256), dim3(512), 0, stream,
                     (const __hip_bfloat16*)Cin, (const __hip_bfloat16*)Wcb,
                     bc, Cpr);
  // 4) attention (writes into Xb, dead after gemm_qkv)
  hipLaunchKernelGGL(attn_kernel, dim3(BB * HH / 32), dim3(256), 0, stream,
                     QKV, Cpr, Xb);
  // 5) output projection -> fp32 d_out with bias (768 blocks)
  hipLaunchKernelGGL(gemm_outp, dim3(768), dim3(512), 0, stream,
                     (const __hip_bfloat16*)Xb, (const __hip_bfloat16*)Wob,
                     bo, (float*)d_out);
}